// Round 1
// baseline (325.488 us; speedup 1.0000x reference)
//
#include <hip/hip_runtime.h>
#include <math.h>

#define E_NUM 320000
#define N_NUM 10000
#define NB8   (N_NUM / 8)           // 1250 blocks (embed)
#define NB16  (N_NUM / 16)          // 625 blocks (layer)
#define TAB   2048

typedef unsigned short ushort_t;
typedef short short8_t __attribute__((ext_vector_type(8)));   // 8 bf16 (4 VGPRs)
typedef float f32x4    __attribute__((ext_vector_type(4)));   // MFMA acc

// wpack layout (shorts):
//   [0)        6x lin2_w  128x128
//   [98304)    6x lin_w   128x128
//   [196608)   6x lin1_w  128x128
//   [294912)   o1w 128x64
//   [303104)   o2w 64x64
//   [307200)   6x mlp_w1  (K=64 zero-padded)x128  -> 8192 each
//   [356352)   6x mlp_w2  128x128                 -> 16384 each
#define WP_O1   294912
#define WP_O2   303104
#define WP_W1T  307200
#define WP_W2T  356352
#define WP_TOT  454656

#define HB  1250                       // hist blocks ((E+255)/256)
#define PB  ((WP_TOT + 255) / 256)     // 1776 pack blocks
#define SCB 1250                       // scatter blocks

__device__ __forceinline__ float ssp_f(float x) {
    return fmaxf(x, 0.f) + __logf(1.f + __expf(-fabsf(x))) - 0.69314718056f;
}

__device__ __forceinline__ float bf2f(ushort_t u) {
    union { unsigned int i; float f; } v;
    v.i = ((unsigned int)u) << 16;
    return v.f;
}
__device__ __forceinline__ ushort_t f2bf(float f) {
    union { float f; unsigned int i; } v;
    v.f = f;
    unsigned int u = v.i;
    unsigned int r = (u + 0x7FFFu + ((u >> 16) & 1u)) >> 16;   // RNE
    return (ushort_t)r;
}

// ---------------------------------------------------------------------------
// fused: counting-sort histogram (blocks [0,HB)) + weight pack (blocks [HB,..))
__global__ __launch_bounds__(256) void hist_pack_kernel(const int* __restrict__ ei,
                                                        int* __restrict__ counts,
                                                        const float* __restrict__ lin2_w,
                                                        const float* __restrict__ lin_w,
                                                        const float* __restrict__ lin1_w,
                                                        const float* __restrict__ o1w,
                                                        const float* __restrict__ o2w,
                                                        const float* __restrict__ mlp_w1,
                                                        const float* __restrict__ mlp_w2,
                                                        short* __restrict__ wpack) {
    if (blockIdx.x < HB) {
        int e = blockIdx.x * 256 + threadIdx.x;
        if (e < E_NUM) atomicAdd(&counts[ei[E_NUM + e]], 1);
        return;
    }
    // pack: B-frag order, idx = ((t*KSP + ks)*64 + L)*8 + j
    int idx = (blockIdx.x - HB) * 256 + threadIdx.x;
    const int M128 = 16384;
    if (idx < 18 * M128) {
        int g = idx / M128, r = idx % M128;
        const float* src;
        if (g < 6) src = lin2_w + g * M128;
        else if (g < 12) src = lin_w + (g - 6) * M128;
        else src = lin1_w + (g - 12) * M128;
        int j = r & 7, L = (r >> 3) & 63, ks = (r >> 9) & 3, t = r >> 11;
        int n = t * 16 + (L & 15);
        int k = ks * 32 + (L >> 4) * 8 + j;
        wpack[idx] = (short)f2bf(src[k * 128 + n]);
    } else if (idx < WP_O2) {
        int r = idx - WP_O1;              // o1w: K=128, N=64
        int j = r & 7, L = (r >> 3) & 63, ks = (r >> 9) & 3, t = r >> 11;
        int n = t * 16 + (L & 15);
        int k = ks * 32 + (L >> 4) * 8 + j;
        wpack[idx] = (short)f2bf(o1w[k * 64 + n]);
    } else if (idx < WP_W1T) {
        int r = idx - WP_O2;              // o2w: K=64, N=64
        int j = r & 7, L = (r >> 3) & 63, ks = (r >> 9) & 1, t = r >> 10;
        int n = t * 16 + (L & 15);
        int k = ks * 32 + (L >> 4) * 8 + j;
        wpack[idx] = (short)f2bf(o2w[k * 64 + n]);
    } else if (idx < WP_W2T) {
        int r2 = idx - WP_W1T;            // mlp_w1: K=50 pad to 64, N=128
        int g = r2 / 8192, r = r2 % 8192;
        int j = r & 7, L = (r >> 3) & 63, ks = (r >> 9) & 1, t = r >> 10;
        int n = t * 16 + (L & 15);
        int k = ks * 32 + (L >> 4) * 8 + j;
        float v = (k < 50) ? mlp_w1[g * 6400 + k * 128 + n] : 0.f;
        wpack[idx] = (short)f2bf(v);
    } else if (idx < WP_TOT) {
        int r2 = idx - WP_W2T;            // mlp_w2: K=128, N=128
        int g = r2 / M128, r = r2 % M128;
        int j = r & 7, L = (r >> 3) & 63, ks = (r >> 9) & 3, t = r >> 11;
        int n = t * 16 + (L & 15);
        int k = ks * 32 + (L >> 4) * 8 + j;
        wpack[idx] = (short)f2bf(mlp_w2[g * M128 + k * 128 + n]);
    }
}

// exclusive scan over 10000 bins (single block, 1024 threads)
__global__ __launch_bounds__(1024) void scan_kernel(const int* __restrict__ counts,
                                                    int* __restrict__ offs,
                                                    int* __restrict__ cursor) {
    __shared__ int part[1024];
    const int tid = threadIdx.x;
    const int CH = 10;
    int base = tid * CH;
    int s = 0;
    #pragma unroll
    for (int i = 0; i < CH; ++i) {
        int idx = base + i;
        if (idx < N_NUM) s += counts[idx];
    }
    part[tid] = s;
    __syncthreads();
    for (int off = 1; off < 1024; off <<= 1) {
        int v = (tid >= off) ? part[tid - off] : 0;
        __syncthreads();
        part[tid] += v;
        __syncthreads();
    }
    int run = (tid > 0) ? part[tid - 1] : 0;
    #pragma unroll
    for (int i = 0; i < CH; ++i) {
        int idx = base + i;
        if (idx < N_NUM) {
            offs[idx] = run;
            cursor[idx] = run;
            run += counts[idx];
        }
    }
    if (tid == 1023) offs[N_NUM] = part[1023];
}

// fused: scatter (blocks [0,SCB)) + embed/lin1 (blocks [SCB,..))
// meta = (i0 << 14) | src ; i0 = nearest table row (11 bits), src 14 bits.
__global__ __launch_bounds__(256) void scatter_embed_kernel(const int* __restrict__ ei,
                                                            const float* __restrict__ dist,
                                                            int* __restrict__ cursor,
                                                            int* __restrict__ meta,
                                                            const int* __restrict__ x,
                                                            const float* __restrict__ emb,
                                                            const float* __restrict__ B,
                                                            float* __restrict__ h,
                                                            ushort_t* __restrict__ xf) {
    if (blockIdx.x < SCB) {
        int e = blockIdx.x * 256 + threadIdx.x;
        if (e >= E_NUM) return;
        int d = ei[E_NUM + e];
        int pos = atomicAdd(&cursor[d], 1);
        float t = dist[e] * ((float)(TAB - 1) / 10.0f);
        int i0 = (int)(t + 0.5f);
        if (i0 > TAB - 1) i0 = TAB - 1;
        meta[pos] = (i0 << 14) | ei[e];
        return;
    }
    // embed + lin1: h = emb[x]; xf = bf16(h @ lin1_w[0]). 8 rows/block.
    __shared__ float AT[128][9];
    __shared__ int s_x[8];
    const int tid = threadIdx.x;
    const int n0 = (blockIdx.x - SCB) * 8;

    if (tid < 8) s_x[tid] = x[n0 + tid];
    __syncthreads();
    for (int i = tid; i < 8 * 128; i += 256) {
        int r = i >> 7, c = i & 127;
        float v = emb[s_x[r] * 128 + c];
        AT[c][r] = v;
        h[(size_t)(n0 + r) * 128 + c] = v;
    }
    __syncthreads();

    const int r  = tid & 7;
    const int c0 = (tid >> 3) * 4;
    float acc[4] = {0.f, 0.f, 0.f, 0.f};
    for (int k = 0; k < 128; k += 4) {
        float a[4];
        #pragma unroll
        for (int u = 0; u < 4; ++u) a[u] = AT[k + u][r];
        #pragma unroll
        for (int u = 0; u < 4; ++u) {
            float4 b = *(const float4*)(B + (size_t)(k + u) * 128 + c0);
            acc[0] = fmaf(a[u], b.x, acc[0]);
            acc[1] = fmaf(a[u], b.y, acc[1]);
            acc[2] = fmaf(a[u], b.z, acc[2]);
            acc[3] = fmaf(a[u], b.w, acc[3]);
        }
    }
    ushort4 o;
    o.x = f2bf(acc[0]); o.y = f2bf(acc[1]); o.z = f2bf(acc[2]); o.w = f2bf(acc[3]);
    *(ushort4*)(xf + (size_t)(n0 + r) * 128 + c0) = o;
}

// ---------------------------------------------------------------------------
// MFMA table build: plain row layout tab[l][i][c] (bf16), nearest-neighbor use.
// 16 d-rows/block, 512 threads, 6*(TAB/16) = 768 blocks.
__global__ __launch_bounds__(512) void table_kernel(const short* __restrict__ w1t,
                                                    const float* __restrict__ mlp_b1,
                                                    const short* __restrict__ w2t,
                                                    const float* __restrict__ mlp_b2,
                                                    ushort_t* __restrict__ tabB) {
    __shared__ short EA[16 * 72];    // bf16 gaussians, K padded to 64
    __shared__ short HD[16 * 136];   // bf16 hidden
    const int tid = threadIdx.x;
    const int wv = tid >> 6;
    const int lane = tid & 63;
    const int l = blockIdx.x >> 7;              // / (TAB/16 = 128)
    const int r0 = (blockIdx.x & 127) * 16;
    const float DG = 10.0f / (float)(TAB - 1);
    const float STEP = 10.0f / 49.0f;
    const float COEFF = -0.5f / (STEP * STEP);

    for (int i = tid; i < 16 * 64; i += 512) {
        int r = i >> 6, k = i & 63;
        float v = 0.f;
        if (k < 50) {
            float d = (float)(r0 + r) * DG;
            float t = d - (float)k * STEP;
            v = __expf(COEFF * t * t);
        }
        EA[r * 72 + k] = (short)f2bf(v);
    }
    __syncthreads();

    const int m = lane & 15, q = lane >> 4;

    // stage 1: hidden = ssp(ea @ w1 + b1), K=64 (padded)
    {
        f32x4 acc = {0.f, 0.f, 0.f, 0.f};
        #pragma unroll
        for (int ks = 0; ks < 2; ++ks) {
            short8_t a = *(const short8_t*)(EA + m * 72 + ks * 32 + q * 8);
            short8_t b = *(const short8_t*)(w1t + l * 8192 + (wv * 2 + ks) * 512 + lane * 8);
            acc = __builtin_amdgcn_mfma_f32_16x16x32_bf16(a, b, acc, 0, 0, 0);
        }
        float bv = mlp_b1[l * 128 + wv * 16 + m];
        #pragma unroll
        for (int i = 0; i < 4; ++i)
            HD[(q * 4 + i) * 136 + wv * 16 + m] = (short)f2bf(ssp_f(acc[i] + bv));
    }
    __syncthreads();

    // stage 2: W = hidden @ w2 + b2, *C(d), plain row write
    {
        f32x4 acc = {0.f, 0.f, 0.f, 0.f};
        #pragma unroll
        for (int ks = 0; ks < 4; ++ks) {
            short8_t a = *(const short8_t*)(HD + m * 136 + ks * 32 + q * 8);
            short8_t b = *(const short8_t*)(w2t + l * 16384 + (wv * 4 + ks) * 512 + lane * 8);
            acc = __builtin_amdgcn_mfma_f32_16x16x32_bf16(a, b, acc, 0, 0, 0);
        }
        int col = wv * 16 + m;
        float bv = mlp_b2[l * 128 + col];
        ushort_t* tl = tabB + (size_t)l * TAB * 128;
        #pragma unroll
        for (int i = 0; i < 4; ++i) {
            int row = r0 + q * 4 + i;
            float d = (float)row * DG;
            float C = 0.5f * (__cosf(d * 0.31415926535f) + 1.0f);
            tl[(size_t)row * 128 + col] = f2bf((acc[i] + bv) * C);
        }
    }
}

// ---------------------------------------------------------------------------
// nearest-neighbor accumulate: 8 cols/lane, one edge
__device__ __forceinline__ void nacc8(short8_t x, short8_t t, float* o) {
    #pragma unroll
    for (int j = 0; j < 8; ++j)
        o[j] = fmaf(bf2f((ushort_t)x[j]), bf2f((ushort_t)t[j]), o[j]);
}

// ---------------------------------------------------------------------------
// Fused MFMA layer kernel: 16 nodes/block, 512 threads (8 waves).
// phase A: each node's edge list split in two halves; waves 0-3 run the first
//          halves (quarter-wave streams), waves 4-7 the second halves.
//          Stream A deposits f32 partials in LDS P; stream B adds + writes A1.
// MFMA stages: wave wv computes col-tile t = wv (one 16-col tile per wave).
template <bool LAST>
__global__ __launch_bounds__(512) void layer_kernel(const int* __restrict__ offs,
                                                    const int* __restrict__ meta,
                                                    const ushort_t* __restrict__ xf,
                                                    const ushort_t* __restrict__ tabB,
                                                    const short* __restrict__ w2p,
                                                    const float* __restrict__ lin2_b,
                                                    const short* __restrict__ wlp,
                                                    const float* __restrict__ lin_b,
                                                    const short* __restrict__ w1p,
                                                    float* __restrict__ h,
                                                    ushort_t* __restrict__ xf_out,
                                                    const short* __restrict__ o1p,
                                                    const float* __restrict__ o1b,
                                                    const short* __restrict__ o2p,
                                                    const float* __restrict__ o2b,
                                                    float* __restrict__ gs) {
    __shared__ short A1[16 * 136];   // bf16, row stride 136 shorts (272 B)
    __shared__ short A2[16 * 136];
    __shared__ float P[16 * 128];    // f32 partials from stream A
    __shared__ float red[4][64];
    const int tid = threadIdx.x;
    const int n0 = blockIdx.x * 16;
    const int wv = tid >> 6;         // 0..7
    const int lane = tid & 63;
    const int strm = wv >> 2;        // 0 = first half, 1 = second half

    // ---- phase A: dual-stream quarter-wave edge walk, nearest table row ----
    {
        const int qt = lane >> 4;        // 0..3
        const int c8 = (lane & 15) * 8;  // 8 cols/lane
        const int row = (wv & 3) * 4 + qt;   // 0..15
        const int node = n0 + row;
        int s0 = offs[node];
        int s1 = offs[node + 1];
        int mid = s0 + ((s1 - s0) >> 1);
        int e   = strm ? mid : s0;
        int end = strm ? s1  : mid;

        float accA[8] = {0.f, 0.f, 0.f, 0.f, 0.f, 0.f, 0.f, 0.f};
        float accB[8] = {0.f, 0.f, 0.f, 0.f, 0.f, 0.f, 0.f, 0.f};

        for (; e + 8 <= end; e += 8) {
            int m[8];
            #pragma unroll
            for (int u = 0; u < 8; ++u) m[u] = meta[e + u];
            short8_t xv[8], tv[8];
            #pragma unroll
            for (int u = 0; u < 8; ++u) {
                xv[u] = *(const short8_t*)(xf + (size_t)(m[u] & 0x3FFF) * 128 + c8);
                tv[u] = *(const short8_t*)(tabB + (size_t)((unsigned)m[u] >> 14) * 128 + c8);
            }
            #pragma unroll
            for (int u = 0; u < 8; ++u)
                nacc8(xv[u], tv[u], (u & 1) ? accB : accA);
        }
        for (; e + 4 <= end; e += 4) {
            int m[4];
            #pragma unroll
            for (int u = 0; u < 4; ++u) m[u] = meta[e + u];
            short8_t xv[4], tv[4];
            #pragma unroll
            for (int u = 0; u < 4; ++u) {
                xv[u] = *(const short8_t*)(xf + (size_t)(m[u] & 0x3FFF) * 128 + c8);
                tv[u] = *(const short8_t*)(tabB + (size_t)((unsigned)m[u] >> 14) * 128 + c8);
            }
            #pragma unroll
            for (int u = 0; u < 4; ++u)
                nacc8(xv[u], tv[u], (u & 1) ? accB : accA);
        }
        for (; e < end; ++e) {
            int mm = meta[e];
            short8_t xv = *(const short8_t*)(xf + (size_t)(mm & 0x3FFF) * 128 + c8);
            short8_t tv = *(const short8_t*)(tabB + (size_t)((unsigned)mm >> 14) * 128 + c8);
            nacc8(xv, tv, accA);
        }

        if (!strm) {
            #pragma unroll
            for (int j = 0; j < 8; ++j)
                P[row * 128 + c8 + j] = accA[j] + accB[j];
        }
        __syncthreads();
        if (strm) {
            short8_t out;
            #pragma unroll
            for (int j = 0; j < 8; ++j)
                out[j] = (short)f2bf(accA[j] + accB[j] + P[row * 128 + c8 + j]);
            *(short8_t*)&A1[row * 136 + c8] = out;
        }
    }
    __syncthreads();

    const int m = lane & 15, q = lane >> 4;
    const int t = wv;                // col-tile per wave

    // ---- stage 1: t = ssp(agg @ lin2_w + lin2_b) -> A2 ----
    {
        f32x4 acc = {0.f, 0.f, 0.f, 0.f};
        #pragma unroll
        for (int ks = 0; ks < 4; ++ks) {
            short8_t a = *(const short8_t*)(A1 + m * 136 + ks * 32 + q * 8);
            short8_t b = *(const short8_t*)(w2p + (t * 4 + ks) * 512 + lane * 8);
            acc = __builtin_amdgcn_mfma_f32_16x16x32_bf16(a, b, acc, 0, 0, 0);
        }
        float bv = lin2_b[t * 16 + m];
        #pragma unroll
        for (int i = 0; i < 4; ++i)
            A2[(q * 4 + i) * 136 + t * 16 + m] = (short)f2bf(ssp_f(acc[i] + bv));
    }
    __syncthreads();

    // ---- stage 2: h_new = h + t @ lin_w + lin_b -> A1 (+ global h if !LAST) ----
    {
        f32x4 acc = {0.f, 0.f, 0.f, 0.f};
        #pragma unroll
        for (int ks = 0; ks < 4; ++ks) {
            short8_t a = *(const short8_t*)(A2 + m * 136 + ks * 32 + q * 8);
            short8_t b = *(const short8_t*)(wlp + (t * 4 + ks) * 512 + lane * 8);
            acc = __builtin_amdgcn_mfma_f32_16x16x32_bf16(a, b, acc, 0, 0, 0);
        }
        float bv = lin_b[t * 16 + m];
        #pragma unroll
        for (int i = 0; i < 4; ++i) {
            int r = q * 4 + i;
            int grow = n0 + r;
            float h0 = h[(size_t)grow * 128 + t * 16 + m];
            float hn = h0 + acc[i] + bv;
            if (!LAST) h[(size_t)grow * 128 + t * 16 + m] = hn;
            A1[r * 136 + t * 16 + m] = (short)f2bf(hn);
        }
    }
    __syncthreads();

    if constexpr (!LAST) {
        // ---- stage 3: xf_out = bf16(h_new @ lin1_next) ----
        f32x4 acc = {0.f, 0.f, 0.f, 0.f};
        #pragma unroll
        for (int ks = 0; ks < 4; ++ks) {
            short8_t a = *(const short8_t*)(A1 + m * 136 + ks * 32 + q * 8);
            short8_t b = *(const short8_t*)(w1p + (t * 4 + ks) * 512 + lane * 8);
            acc = __builtin_amdgcn_mfma_f32_16x16x32_bf16(a, b, acc, 0, 0, 0);
        }
        #pragma unroll
        for (int i = 0; i < 4; ++i) {
            int r = q * 4 + i;
            int grow = n0 + r;
            xf_out[(size_t)grow * 128 + t * 16 + m] = f2bf(acc[i]);
        }
    } else {
        // ---- fused head: t1 = ssp(h_new@o1w+o1b); t2 = t1@o2w+o2b; colsum ----
        if (wv < 4) {
            f32x4 acc = {0.f, 0.f, 0.f, 0.f};
            #pragma unroll
            for (int ks = 0; ks < 4; ++ks) {
                short8_t a = *(const short8_t*)(A1 + m * 136 + ks * 32 + q * 8);
                short8_t b = *(const short8_t*)(o1p + (wv * 4 + ks) * 512 + lane * 8);
                acc = __builtin_amdgcn_mfma_f32_16x16x32_bf16(a, b, acc, 0, 0, 0);
            }
            float bv = o1b[wv * 16 + m];
            #pragma unroll
            for (int i = 0; i < 4; ++i) {
                int r = q * 4 + i;
                A2[r * 136 + wv * 16 + m] = (short)f2bf(ssp_f(acc[i] + bv));
            }
        }
        __syncthreads();
        if (wv < 4) {
            f32x4 acc = {0.f, 0.f, 0.f, 0.f};
            #pragma unroll
            for (int ks = 0; ks < 2; ++ks) {
                short8_t a = *(const short8_t*)(A2 + m * 136 + ks * 32 + q * 8);
                short8_t b = *(const short8_t*)(o2p + (wv * 2 + ks) * 512 + lane * 8);
                acc = __builtin_amdgcn_mfma_f32_16x16x32_bf16(a, b, acc, 0, 0, 0);
            }
            float bv = o2b[wv * 16 + m];
            float part = acc[0] + acc[1] + acc[2] + acc[3] + 4.0f * bv;
            red[q][wv * 16 + m] = part;
        }
        __syncthreads();
        if (tid < 64) {
            float s = red[0][tid] + red[1][tid] + red[2][tid] + red[3][tid];
            atomicAdd(&gs[tid], s);
        }
    }
}

// out[i] = ro_b[i] + sum_k gs[k] * ro_w[k][i]
__global__ void final_kernel(const float* __restrict__ gs,
                             const float* __restrict__ ro_w,
                             const float* __restrict__ ro_b,
                             float* __restrict__ out) {
    int i = threadIdx.x;
    if (i < 12) {
        float s = ro_b[i];
        for (int k = 0; k < 64; ++k) s = fmaf(gs[k], ro_w[k * 12 + i], s);
        out[i] = s;
    }
}

// ---------------------------------------------------------------------------
extern "C" void kernel_launch(void* const* d_in, const int* in_sizes, int n_in,
                              void* d_out, int out_size, void* d_ws, size_t ws_size,
                              hipStream_t stream) {
    const int*   x      = (const int*)d_in[0];
    const int*   ei     = (const int*)d_in[1];
    const float* dist   = (const float*)d_in[2];
    const float* emb    = (const float*)d_in[3];
    const float* mlp_w1 = (const float*)d_in[4];
    const float* mlp_b1 = (const float*)d_in[5];
    const float* mlp_w2 = (const float*)d_in[6];
    const float* mlp_b2 = (const float*)d_in[7];
    const float* lin1_w = (const float*)d_in[8];
    const float* lin2_w = (const float*)d_in[9];
    const float* lin2_b = (const float*)d_in[10];
    const float* lin_w  = (const float*)d_in[11];
    const float* lin_b  = (const float*)d_in[12];
    const float* out1_w = (const float*)d_in[13];
    const float* out1_b = (const float*)d_in[14];
    const float* out2_w = (const float*)d_in[15];
    const float* out2_b = (const float*)d_in[16];
    const float* ro_w   = (const float*)d_in[17];
    const float* ro_b   = (const float*)d_in[18];
    float* out = (float*)d_out;

    // workspace layout
    char* base = (char*)d_ws;
    float*    h     = (float*)base;     base += (size_t)N_NUM * 128 * 4;
    ushort_t* tabB  = (ushort_t*)base;  base += (size_t)6 * TAB * 128 * 2;
    ushort_t* xf0   = (ushort_t*)base;  base += (size_t)N_NUM * 128 * 2;
    ushort_t* xf1   = (ushort_t*)base;  base += (size_t)N_NUM * 128 * 2;
    int*      meta  = (int*)base;       base += (size_t)E_NUM * 4;
    short*    wpack = (short*)base;     base += (size_t)WP_TOT * 2;
    float*    gs    = (float*)base;     base += 64 * 4;
    int*      offs  = (int*)base;       base += (N_NUM + 1) * 4;
    int*      cursor= (int*)base;       base += N_NUM * 4;
    int*      counts= (int*)base;       base += N_NUM * 4;

    hipMemsetAsync(counts, 0, N_NUM * sizeof(int), stream);
    hipMemsetAsync(gs, 0, 64 * sizeof(float), stream);

    // fused: histogram (dst counts) + weight pack
    hist_pack_kernel<<<HB + PB, 256, 0, stream>>>(
        ei, counts, lin2_w, lin_w, lin1_w, out1_w, out2_w, mlp_w1, mlp_w2, wpack);

    // exclusive scan
    scan_kernel<<<1, 1024, 0, stream>>>(counts, offs, cursor);

    // fused: scatter edges to dst-sorted order + embed/lin1 front
    scatter_embed_kernel<<<SCB + NB8, 256, 0, stream>>>(
        ei, dist, cursor, meta, x, emb, lin1_w, h, xf0);

    // filter tables via MFMA (needs wpack)
    table_kernel<<<6 * (TAB / 16), 512, 0, stream>>>(
        wpack + WP_W1T, mlp_b1, wpack + WP_W2T, mlp_b2, tabB);

    const short* o1p = wpack + WP_O1;
    const short* o2p = wpack + WP_O2;

    for (int l = 0; l < 6; ++l) {
        ushort_t* xin  = (l & 1) ? xf1 : xf0;
        ushort_t* xout = (l & 1) ? xf0 : xf1;
        const ushort_t* tl = tabB + (size_t)l * TAB * 128;
        const short* w2p = wpack + l * 16384;
        const short* wlp = wpack + (6 + l) * 16384;
        if (l < 5) {
            const short* w1p = wpack + (12 + l + 1) * 16384;   // lin1_w[l+1]
            layer_kernel<false><<<NB16, 512, 0, stream>>>(
                offs, meta, xin, tl,
                w2p, lin2_b + l * 128, wlp, lin_b + l * 128, w1p,
                h, xout, nullptr, nullptr, nullptr, nullptr, nullptr);
        } else {
            layer_kernel<true><<<NB16, 512, 0, stream>>>(
                offs, meta, xin, tl,
                w2p, lin2_b + l * 128, wlp, lin_b + l * 128, nullptr,
                h, nullptr, o1p, out1_b, o2p, out2_b, gs);
        }
    }

    final_kernel<<<1, 64, 0, stream>>>(gs, ro_w, ro_b, out);
}

// Round 2
// 288.297 us; speedup vs baseline: 1.1290x; 1.1290x over previous
//
#include <hip/hip_runtime.h>
#include <math.h>

#define E_NUM 320000
#define N_NUM 10000
#define NB16  (N_NUM / 16)          // 625 blocks (layer / embed)
#define TAB   2048

typedef unsigned short ushort_t;
typedef short short8_t __attribute__((ext_vector_type(8)));   // 8 bf16 (4 VGPRs)
typedef float f32x4    __attribute__((ext_vector_type(4)));   // MFMA acc

// wpack layout (shorts):
//   [0)        6x lin2_w  128x128
//   [98304)    6x lin_w   128x128
//   [196608)   6x lin1_w  128x128
//   [294912)   o1w 128x64
//   [303104)   o2w 64x64
//   [307200)   6x mlp_w1  (K=64 zero-padded)x128  -> 8192 each
//   [356352)   6x mlp_w2  128x128                 -> 16384 each
#define WP_O1   294912
#define WP_O2   303104
#define WP_W1T  307200
#define WP_W2T  356352
#define WP_TOT  454656

#define HB  1250                       // hist blocks (E/256)
#define PB  ((WP_TOT + 255) / 256)     // pack blocks

// fused front kernel partition (512-thread blocks)
#define FK_SC 625                      // scatter blocks (E/512 exactly)
#define FK_TB 768                      // table blocks (6 * TAB/16)
#define FK_EM NB16                     // embed blocks (625)

__device__ __forceinline__ float ssp_f(float x) {
    return fmaxf(x, 0.f) + __logf(1.f + __expf(-fabsf(x))) - 0.69314718056f;
}

__device__ __forceinline__ float bf2f(ushort_t u) {
    union { unsigned int i; float f; } v;
    v.i = ((unsigned int)u) << 16;
    return v.f;
}
__device__ __forceinline__ ushort_t f2bf(float f) {
    union { float f; unsigned int i; } v;
    v.f = f;
    unsigned int u = v.i;
    unsigned int r = (u + 0x7FFFu + ((u >> 16) & 1u)) >> 16;   // RNE
    return (ushort_t)r;
}

// ---------------------------------------------------------------------------
// fused: counting-sort histogram (blocks [0,HB)) + weight pack (blocks [HB,..))
__global__ __launch_bounds__(256) void hist_pack_kernel(const int* __restrict__ ei,
                                                        int* __restrict__ counts,
                                                        const float* __restrict__ lin2_w,
                                                        const float* __restrict__ lin_w,
                                                        const float* __restrict__ lin1_w,
                                                        const float* __restrict__ o1w,
                                                        const float* __restrict__ o2w,
                                                        const float* __restrict__ mlp_w1,
                                                        const float* __restrict__ mlp_w2,
                                                        short* __restrict__ wpack) {
    if (blockIdx.x < HB) {
        int e = blockIdx.x * 256 + threadIdx.x;
        atomicAdd(&counts[ei[E_NUM + e]], 1);
        return;
    }
    // pack: B-frag order, idx = ((t*KSP + ks)*64 + L)*8 + j
    int idx = (blockIdx.x - HB) * 256 + threadIdx.x;
    const int M128 = 16384;
    if (idx < 18 * M128) {
        int g = idx / M128, r = idx % M128;
        const float* src;
        if (g < 6) src = lin2_w + g * M128;
        else if (g < 12) src = lin_w + (g - 6) * M128;
        else src = lin1_w + (g - 12) * M128;
        int j = r & 7, L = (r >> 3) & 63, ks = (r >> 9) & 3, t = r >> 11;
        int n = t * 16 + (L & 15);
        int k = ks * 32 + (L >> 4) * 8 + j;
        wpack[idx] = (short)f2bf(src[k * 128 + n]);
    } else if (idx < WP_O2) {
        int r = idx - WP_O1;              // o1w: K=128, N=64
        int j = r & 7, L = (r >> 3) & 63, ks = (r >> 9) & 3, t = r >> 11;
        int n = t * 16 + (L & 15);
        int k = ks * 32 + (L >> 4) * 8 + j;
        wpack[idx] = (short)f2bf(o1w[k * 64 + n]);
    } else if (idx < WP_W1T) {
        int r = idx - WP_O2;              // o2w: K=64, N=64
        int j = r & 7, L = (r >> 3) & 63, ks = (r >> 9) & 1, t = r >> 10;
        int n = t * 16 + (L & 15);
        int k = ks * 32 + (L >> 4) * 8 + j;
        wpack[idx] = (short)f2bf(o2w[k * 64 + n]);
    } else if (idx < WP_W1T + 6 * 8192 && idx >= WP_W1T) {
        int r2 = idx - WP_W1T;            // mlp_w1: K=50 pad to 64, N=128
        int g = r2 / 8192, r = r2 % 8192;
        int j = r & 7, L = (r >> 3) & 63, ks = (r >> 9) & 1, t = r >> 10;
        int n = t * 16 + (L & 15);
        int k = ks * 32 + (L >> 4) * 8 + j;
        float v = (k < 50) ? mlp_w1[g * 6400 + k * 128 + n] : 0.f;
        wpack[idx] = (short)f2bf(v);
    } else if (idx < WP_TOT) {
        int r2 = idx - WP_W2T;            // mlp_w2: K=128, N=128
        int g = r2 / M128, r = r2 % M128;
        int j = r & 7, L = (r >> 3) & 63, ks = (r >> 9) & 3, t = r >> 11;
        int n = t * 16 + (L & 15);
        int k = ks * 32 + (L >> 4) * 8 + j;
        wpack[idx] = (short)f2bf(mlp_w2[g * M128 + k * 128 + n]);
    }
}

// exclusive scan over 10000 bins (single block, 1024 threads)
__global__ __launch_bounds__(1024) void scan_kernel(const int* __restrict__ counts,
                                                    int* __restrict__ offs,
                                                    int* __restrict__ cursor) {
    __shared__ int part[1024];
    const int tid = threadIdx.x;
    const int CH = 10;
    int base = tid * CH;
    int s = 0;
    #pragma unroll
    for (int i = 0; i < CH; ++i) {
        int idx = base + i;
        if (idx < N_NUM) s += counts[idx];
    }
    part[tid] = s;
    __syncthreads();
    for (int off = 1; off < 1024; off <<= 1) {
        int v = (tid >= off) ? part[tid - off] : 0;
        __syncthreads();
        part[tid] += v;
        __syncthreads();
    }
    int run = (tid > 0) ? part[tid - 1] : 0;
    #pragma unroll
    for (int i = 0; i < CH; ++i) {
        int idx = base + i;
        if (idx < N_NUM) {
            offs[idx] = run;
            cursor[idx] = run;
            run += counts[idx];
        }
    }
    if (tid == 1023) offs[N_NUM] = part[1023];
}

// ---------------------------------------------------------------------------
// fused front kernel: 512 threads/block
//   blocks [0, FK_SC):              edge scatter (atomic rank into meta)
//   blocks [FK_SC, FK_SC+FK_TB):    MFMA filter-table build
//   blocks [FK_SC+FK_TB, +FK_EM):   embed + lin1_w[0] via MFMA -> h, xf
// meta = (i0 << 14) | src ; i0 = nearest table row (11 bits), src 14 bits.
__global__ __launch_bounds__(512) void front_kernel(const int* __restrict__ ei,
                                                    const float* __restrict__ dist,
                                                    int* __restrict__ cursor,
                                                    int* __restrict__ meta,
                                                    const short* __restrict__ w1t,
                                                    const float* __restrict__ mlp_b1,
                                                    const short* __restrict__ w2t,
                                                    const float* __restrict__ mlp_b2,
                                                    ushort_t* __restrict__ tabB,
                                                    const int* __restrict__ x,
                                                    const float* __restrict__ emb,
                                                    const short* __restrict__ w1p0,
                                                    float* __restrict__ h,
                                                    ushort_t* __restrict__ xf) {
    __shared__ short EA[16 * 72];    // table: bf16 gaussians (also embed A-tile aliasable, kept separate)
    __shared__ short HD[16 * 136];   // table: bf16 hidden / embed: A-tile
    __shared__ int s_x[16];
    const int tid = threadIdx.x;

    if (blockIdx.x < FK_SC) {
        // ---- scatter: 625 * 512 = 320000 exactly ----
        int e = blockIdx.x * 512 + tid;
        int d = ei[E_NUM + e];
        int pos = atomicAdd(&cursor[d], 1);
        float t = dist[e] * ((float)(TAB - 1) / 10.0f);
        int i0 = (int)(t + 0.5f);
        if (i0 > TAB - 1) i0 = TAB - 1;
        meta[pos] = (i0 << 14) | ei[e];
        return;
    }

    const int wv = tid >> 6;
    const int lane = tid & 63;
    const int m = lane & 15, q = lane >> 4;

    if (blockIdx.x < FK_SC + FK_TB) {
        // ---- MFMA table build: 16 d-rows/block ----
        const int bt = blockIdx.x - FK_SC;
        const int l = bt >> 7;              // / (TAB/16 = 128)
        const int r0 = (bt & 127) * 16;
        const float DG = 10.0f / (float)(TAB - 1);
        const float STEP = 10.0f / 49.0f;
        const float COEFF = -0.5f / (STEP * STEP);

        for (int i = tid; i < 16 * 64; i += 512) {
            int r = i >> 6, k = i & 63;
            float v = 0.f;
            if (k < 50) {
                float d = (float)(r0 + r) * DG;
                float t = d - (float)k * STEP;
                v = __expf(COEFF * t * t);
            }
            EA[r * 72 + k] = (short)f2bf(v);
        }
        __syncthreads();

        // stage 1: hidden = ssp(ea @ w1 + b1), K=64 (padded)
        {
            f32x4 acc = {0.f, 0.f, 0.f, 0.f};
            #pragma unroll
            for (int ks = 0; ks < 2; ++ks) {
                short8_t a = *(const short8_t*)(EA + m * 72 + ks * 32 + q * 8);
                short8_t b = *(const short8_t*)(w1t + l * 8192 + (wv * 2 + ks) * 512 + lane * 8);
                acc = __builtin_amdgcn_mfma_f32_16x16x32_bf16(a, b, acc, 0, 0, 0);
            }
            float bv = mlp_b1[l * 128 + wv * 16 + m];
            #pragma unroll
            for (int i = 0; i < 4; ++i)
                HD[(q * 4 + i) * 136 + wv * 16 + m] = (short)f2bf(ssp_f(acc[i] + bv));
        }
        __syncthreads();

        // stage 2: W = hidden @ w2 + b2, *C(d)
        {
            f32x4 acc = {0.f, 0.f, 0.f, 0.f};
            #pragma unroll
            for (int ks = 0; ks < 4; ++ks) {
                short8_t a = *(const short8_t*)(HD + m * 136 + ks * 32 + q * 8);
                short8_t b = *(const short8_t*)(w2t + l * 16384 + (wv * 4 + ks) * 512 + lane * 8);
                acc = __builtin_amdgcn_mfma_f32_16x16x32_bf16(a, b, acc, 0, 0, 0);
            }
            int col = wv * 16 + m;
            float bv = mlp_b2[l * 128 + col];
            ushort_t* tl = tabB + (size_t)l * TAB * 128;
            #pragma unroll
            for (int i = 0; i < 4; ++i) {
                int row = r0 + q * 4 + i;
                float d = (float)row * DG;
                float C = 0.5f * (__cosf(d * 0.31415926535f) + 1.0f);
                tl[(size_t)row * 128 + col] = f2bf((acc[i] + bv) * C);
            }
        }
        return;
    }

    // ---- embed + lin1[0] via MFMA: 16 nodes/block ----
    {
        const int n0 = (blockIdx.x - FK_SC - FK_TB) * 16;
        if (tid < 16) s_x[tid] = x[n0 + tid];
        __syncthreads();
        {
            // 512 threads x 4 elems = 16 x 128
            int r = tid >> 5;            // 0..15
            int c4 = (tid & 31) * 4;     // 0..124
            float4 v = *(const float4*)(emb + (size_t)s_x[r] * 128 + c4);
            *(float4*)(h + (size_t)(n0 + r) * 128 + c4) = v;
            short4 o;
            o.x = (short)f2bf(v.x); o.y = (short)f2bf(v.y);
            o.z = (short)f2bf(v.z); o.w = (short)f2bf(v.w);
            *(short4*)(HD + r * 136 + c4) = o;
        }
        __syncthreads();
        // wave wv computes col-tile t = wv
        f32x4 acc = {0.f, 0.f, 0.f, 0.f};
        #pragma unroll
        for (int ks = 0; ks < 4; ++ks) {
            short8_t a = *(const short8_t*)(HD + m * 136 + ks * 32 + q * 8);
            short8_t b = *(const short8_t*)(w1p0 + (wv * 4 + ks) * 512 + lane * 8);
            acc = __builtin_amdgcn_mfma_f32_16x16x32_bf16(a, b, acc, 0, 0, 0);
        }
        #pragma unroll
        for (int i = 0; i < 4; ++i) {
            int grow = n0 + q * 4 + i;
            xf[(size_t)grow * 128 + wv * 16 + m] = f2bf(acc[i]);
        }
    }
}

// ---------------------------------------------------------------------------
// nearest-neighbor accumulate: 8 cols/lane, one edge
__device__ __forceinline__ void nacc8(short8_t x, short8_t t, float* o) {
    #pragma unroll
    for (int j = 0; j < 8; ++j)
        o[j] = fmaf(bf2f((ushort_t)x[j]), bf2f((ushort_t)t[j]), o[j]);
}

// ---------------------------------------------------------------------------
// Fused MFMA layer kernel: 16 nodes/block, 512 threads (8 waves).
// phase A: each node's edge list split in two halves; waves 0-3 run the first
//          halves (quarter-wave streams), waves 4-7 the second halves.
//          meta loads are software-pipelined one iteration ahead.
// MFMA stages: wave wv computes col-tile t = wv.
template <bool LAST>
__global__ __launch_bounds__(512) void layer_kernel(const int* __restrict__ offs,
                                                    const int* __restrict__ meta,
                                                    const ushort_t* __restrict__ xf,
                                                    const ushort_t* __restrict__ tabB,
                                                    const short* __restrict__ w2p,
                                                    const float* __restrict__ lin2_b,
                                                    const short* __restrict__ wlp,
                                                    const float* __restrict__ lin_b,
                                                    const short* __restrict__ w1p,
                                                    float* __restrict__ h,
                                                    ushort_t* __restrict__ xf_out,
                                                    const short* __restrict__ o1p,
                                                    const float* __restrict__ o1b,
                                                    const short* __restrict__ o2p,
                                                    const float* __restrict__ o2b,
                                                    float* __restrict__ gs) {
    __shared__ short A1[16 * 136];   // bf16, row stride 136 shorts (272 B)
    __shared__ short A2[16 * 136];
    __shared__ float P[16 * 128];    // f32 partials from stream A
    __shared__ float red[4][64];
    const int tid = threadIdx.x;
    const int n0 = blockIdx.x * 16;
    const int wv = tid >> 6;         // 0..7
    const int lane = tid & 63;
    const int strm = wv >> 2;        // 0 = first half, 1 = second half

    // ---- phase A: dual-stream quarter-wave edge walk, nearest table row ----
    {
        const int qt = lane >> 4;        // 0..3
        const int c8 = (lane & 15) * 8;  // 8 cols/lane
        const int row = (wv & 3) * 4 + qt;   // 0..15
        const int node = n0 + row;
        int s0 = offs[node];
        int s1 = offs[node + 1];
        int mid = s0 + ((s1 - s0) >> 1);
        int e   = strm ? mid : s0;
        int end = strm ? s1  : mid;

        float accA[8] = {0.f, 0.f, 0.f, 0.f, 0.f, 0.f, 0.f, 0.f};
        float accB[8] = {0.f, 0.f, 0.f, 0.f, 0.f, 0.f, 0.f, 0.f};

        // software-pipelined 8-edge main loop (meta prefetched 1 iter ahead)
        int mc[8];
        bool have = (e + 8 <= end);
        if (have) {
            #pragma unroll
            for (int u = 0; u < 8; ++u) mc[u] = meta[e + u];
        }
        while (have) {
            bool nxt = (e + 16 <= end);
            int mn[8];
            if (nxt) {
                #pragma unroll
                for (int u = 0; u < 8; ++u) mn[u] = meta[e + 8 + u];
            }
            short8_t xv[8], tv[8];
            #pragma unroll
            for (int u = 0; u < 8; ++u) {
                xv[u] = *(const short8_t*)(xf + (size_t)(mc[u] & 0x3FFF) * 128 + c8);
                tv[u] = *(const short8_t*)(tabB + (size_t)((unsigned)mc[u] >> 14) * 128 + c8);
            }
            #pragma unroll
            for (int u = 0; u < 8; ++u)
                nacc8(xv[u], tv[u], (u & 1) ? accB : accA);
            #pragma unroll
            for (int u = 0; u < 8; ++u) mc[u] = mn[u];
            e += 8;
            have = nxt;
        }
        if (e + 4 <= end) {
            int mm[4];
            #pragma unroll
            for (int u = 0; u < 4; ++u) mm[u] = meta[e + u];
            short8_t xv[4], tv[4];
            #pragma unroll
            for (int u = 0; u < 4; ++u) {
                xv[u] = *(const short8_t*)(xf + (size_t)(mm[u] & 0x3FFF) * 128 + c8);
                tv[u] = *(const short8_t*)(tabB + (size_t)((unsigned)mm[u] >> 14) * 128 + c8);
            }
            #pragma unroll
            for (int u = 0; u < 4; ++u)
                nacc8(xv[u], tv[u], (u & 1) ? accB : accA);
            e += 4;
        }
        for (; e < end; ++e) {
            int mm = meta[e];
            short8_t xv = *(const short8_t*)(xf + (size_t)(mm & 0x3FFF) * 128 + c8);
            short8_t tv = *(const short8_t*)(tabB + (size_t)((unsigned)mm >> 14) * 128 + c8);
            nacc8(xv, tv, accA);
        }

        if (!strm) {
            #pragma unroll
            for (int j = 0; j < 8; ++j)
                P[row * 128 + c8 + j] = accA[j] + accB[j];
        }
        __syncthreads();
        if (strm) {
            short8_t out;
            #pragma unroll
            for (int j = 0; j < 8; ++j)
                out[j] = (short)f2bf(accA[j] + accB[j] + P[row * 128 + c8 + j]);
            *(short8_t*)&A1[row * 136 + c8] = out;
        }
    }
    __syncthreads();

    const int m = lane & 15, q = lane >> 4;
    const int t = wv;                // col-tile per wave

    // ---- stage 1: t = ssp(agg @ lin2_w + lin2_b) -> A2 ----
    {
        f32x4 acc = {0.f, 0.f, 0.f, 0.f};
        #pragma unroll
        for (int ks = 0; ks < 4; ++ks) {
            short8_t a = *(const short8_t*)(A1 + m * 136 + ks * 32 + q * 8);
            short8_t b = *(const short8_t*)(w2p + (t * 4 + ks) * 512 + lane * 8);
            acc = __builtin_amdgcn_mfma_f32_16x16x32_bf16(a, b, acc, 0, 0, 0);
        }
        float bv = lin2_b[t * 16 + m];
        #pragma unroll
        for (int i = 0; i < 4; ++i)
            A2[(q * 4 + i) * 136 + t * 16 + m] = (short)f2bf(ssp_f(acc[i] + bv));
    }
    __syncthreads();

    // ---- stage 2: h_new = h + t @ lin_w + lin_b -> A1 (+ global h if !LAST) ----
    {
        f32x4 acc = {0.f, 0.f, 0.f, 0.f};
        #pragma unroll
        for (int ks = 0; ks < 4; ++ks) {
            short8_t a = *(const short8_t*)(A2 + m * 136 + ks * 32 + q * 8);
            short8_t b = *(const short8_t*)(wlp + (t * 4 + ks) * 512 + lane * 8);
            acc = __builtin_amdgcn_mfma_f32_16x16x32_bf16(a, b, acc, 0, 0, 0);
        }
        float bv = lin_b[t * 16 + m];
        #pragma unroll
        for (int i = 0; i < 4; ++i) {
            int r = q * 4 + i;
            int grow = n0 + r;
            float h0 = h[(size_t)grow * 128 + t * 16 + m];
            float hn = h0 + acc[i] + bv;
            if (!LAST) h[(size_t)grow * 128 + t * 16 + m] = hn;
            A1[r * 136 + t * 16 + m] = (short)f2bf(hn);
        }
    }
    __syncthreads();

    if constexpr (!LAST) {
        // ---- stage 3: xf_out = bf16(h_new @ lin1_next) ----
        f32x4 acc = {0.f, 0.f, 0.f, 0.f};
        #pragma unroll
        for (int ks = 0; ks < 4; ++ks) {
            short8_t a = *(const short8_t*)(A1 + m * 136 + ks * 32 + q * 8);
            short8_t b = *(const short8_t*)(w1p + (t * 4 + ks) * 512 + lane * 8);
            acc = __builtin_amdgcn_mfma_f32_16x16x32_bf16(a, b, acc, 0, 0, 0);
        }
        #pragma unroll
        for (int i = 0; i < 4; ++i) {
            int r = q * 4 + i;
            int grow = n0 + r;
            xf_out[(size_t)grow * 128 + t * 16 + m] = f2bf(acc[i]);
        }
    } else {
        // ---- fused head: t1 = ssp(h_new@o1w+o1b); t2 = t1@o2w+o2b; colsum ----
        if (wv < 4) {
            f32x4 acc = {0.f, 0.f, 0.f, 0.f};
            #pragma unroll
            for (int ks = 0; ks < 4; ++ks) {
                short8_t a = *(const short8_t*)(A1 + m * 136 + ks * 32 + q * 8);
                short8_t b = *(const short8_t*)(o1p + (wv * 4 + ks) * 512 + lane * 8);
                acc = __builtin_amdgcn_mfma_f32_16x16x32_bf16(a, b, acc, 0, 0, 0);
            }
            float bv = o1b[wv * 16 + m];
            #pragma unroll
            for (int i = 0; i < 4; ++i) {
                int r = q * 4 + i;
                A2[r * 136 + wv * 16 + m] = (short)f2bf(ssp_f(acc[i] + bv));
            }
        }
        __syncthreads();
        if (wv < 4) {
            f32x4 acc = {0.f, 0.f, 0.f, 0.f};
            #pragma unroll
            for (int ks = 0; ks < 2; ++ks) {
                short8_t a = *(const short8_t*)(A2 + m * 136 + ks * 32 + q * 8);
                short8_t b = *(const short8_t*)(o2p + (wv * 2 + ks) * 512 + lane * 8);
                acc = __builtin_amdgcn_mfma_f32_16x16x32_bf16(a, b, acc, 0, 0, 0);
            }
            float bv = o2b[wv * 16 + m];
            float part = acc[0] + acc[1] + acc[2] + acc[3] + 4.0f * bv;
            red[q][wv * 16 + m] = part;
        }
        __syncthreads();
        if (tid < 64) {
            float s = red[0][tid] + red[1][tid] + red[2][tid] + red[3][tid];
            atomicAdd(&gs[tid], s);
        }
    }
}

// out[i] = ro_b[i] + sum_k gs[k] * ro_w[k][i]
__global__ void final_kernel(const float* __restrict__ gs,
                             const float* __restrict__ ro_w,
                             const float* __restrict__ ro_b,
                             float* __restrict__ out) {
    int i = threadIdx.x;
    if (i < 12) {
        float s = ro_b[i];
        for (int k = 0; k < 64; ++k) s = fmaf(gs[k], ro_w[k * 12 + i], s);
        out[i] = s;
    }
}

// ---------------------------------------------------------------------------
extern "C" void kernel_launch(void* const* d_in, const int* in_sizes, int n_in,
                              void* d_out, int out_size, void* d_ws, size_t ws_size,
                              hipStream_t stream) {
    const int*   x      = (const int*)d_in[0];
    const int*   ei     = (const int*)d_in[1];
    const float* dist   = (const float*)d_in[2];
    const float* emb    = (const float*)d_in[3];
    const float* mlp_w1 = (const float*)d_in[4];
    const float* mlp_b1 = (const float*)d_in[5];
    const float* mlp_w2 = (const float*)d_in[6];
    const float* mlp_b2 = (const float*)d_in[7];
    const float* lin1_w = (const float*)d_in[8];
    const float* lin2_w = (const float*)d_in[9];
    const float* lin2_b = (const float*)d_in[10];
    const float* lin_w  = (const float*)d_in[11];
    const float* lin_b  = (const float*)d_in[12];
    const float* out1_w = (const float*)d_in[13];
    const float* out1_b = (const float*)d_in[14];
    const float* out2_w = (const float*)d_in[15];
    const float* out2_b = (const float*)d_in[16];
    const float* ro_w   = (const float*)d_in[17];
    const float* ro_b   = (const float*)d_in[18];
    float* out = (float*)d_out;

    // workspace layout
    char* base = (char*)d_ws;
    float*    h     = (float*)base;     base += (size_t)N_NUM * 128 * 4;
    ushort_t* tabB  = (ushort_t*)base;  base += (size_t)6 * TAB * 128 * 2;
    ushort_t* xf0   = (ushort_t*)base;  base += (size_t)N_NUM * 128 * 2;
    ushort_t* xf1   = (ushort_t*)base;  base += (size_t)N_NUM * 128 * 2;
    int*      meta  = (int*)base;       base += (size_t)E_NUM * 4;
    short*    wpack = (short*)base;     base += (size_t)WP_TOT * 2;
    float*    gs    = (float*)base;     base += 64 * 4;
    int*      offs  = (int*)base;       base += (N_NUM + 1) * 4;
    int*      cursor= (int*)base;       base += N_NUM * 4;
    int*      counts= (int*)base;       base += N_NUM * 4;

    hipMemsetAsync(counts, 0, N_NUM * sizeof(int), stream);
    hipMemsetAsync(gs, 0, 64 * sizeof(float), stream);

    // fused: histogram (dst counts) + weight pack
    hist_pack_kernel<<<HB + PB, 256, 0, stream>>>(
        ei, counts, lin2_w, lin_w, lin1_w, out1_w, out2_w, mlp_w1, mlp_w2, wpack);

    // exclusive scan
    scan_kernel<<<1, 1024, 0, stream>>>(counts, offs, cursor);

    // fused: scatter + MFMA table build + embed/lin1[0]
    front_kernel<<<FK_SC + FK_TB + FK_EM, 512, 0, stream>>>(
        ei, dist, cursor, meta,
        wpack + WP_W1T, mlp_b1, wpack + WP_W2T, mlp_b2, tabB,
        x, emb, wpack + 12 * 16384, h, xf0);

    const short* o1p = wpack + WP_O1;
    const short* o2p = wpack + WP_O2;

    for (int l = 0; l < 6; ++l) {
        ushort_t* xin  = (l & 1) ? xf1 : xf0;
        ushort_t* xout = (l & 1) ? xf0 : xf1;
        const ushort_t* tl = tabB + (size_t)l * TAB * 128;
        const short* w2p = wpack + l * 16384;
        const short* wlp = wpack + (6 + l) * 16384;
        if (l < 5) {
            const short* w1p = wpack + (12 + l + 1) * 16384;   // lin1_w[l+1]
            layer_kernel<false><<<NB16, 512, 0, stream>>>(
                offs, meta, xin, tl,
                w2p, lin2_b + l * 128, wlp, lin_b + l * 128, w1p,
                h, xout, nullptr, nullptr, nullptr, nullptr, nullptr);
        } else {
            layer_kernel<true><<<NB16, 512, 0, stream>>>(
                offs, meta, xin, tl,
                w2p, lin2_b + l * 128, wlp, lin_b + l * 128, nullptr,
                h, nullptr, o1p, out1_b, o2p, out2_b, gs);
        }
    }

    final_kernel<<<1, 64, 0, stream>>>(gs, ro_w, ro_b, out);
}